// Round 14
// baseline (245.420 us; speedup 1.0000x reference)
//
#include <hip/hip_runtime.h>
#include <hip/hip_bf16.h>

// NodeModel fused GNN block, round 14 = round 13 with BARRIER-FREE per-wave
// pipelined edge_E: each wave owns 4 tiles x 16 edges + a private LDS
// double-buffer -> no __syncthreads in the hot kernel at all; waves slip
// independently so the HBM pipe never drains. Grid 2500 blocks.
//   memset cnt; prep_hist; scanA; [scanBC|gemm_y]; edge_E; mlp_h1out

typedef __bf16 bf16x8 __attribute__((ext_vector_type(8)));
typedef float f32x4v __attribute__((ext_vector_type(4)));
typedef float f32x2v __attribute__((ext_vector_type(2)));
typedef unsigned int u32x2v __attribute__((ext_vector_type(2)));

#define NN 40000
#define NE 640000
#define TPW 4   // tiles (of 16 edges) per wave

__device__ inline bf16x8 cvt8(const float* __restrict__ p) {
  f32x4v a = *(const f32x4v*)p;
  f32x4v b = *(const f32x4v*)(p + 4);
  bf16x8 r;
  r[0] = (__bf16)a[0]; r[1] = (__bf16)a[1]; r[2] = (__bf16)a[2]; r[3] = (__bf16)a[3];
  r[4] = (__bf16)b[0]; r[5] = (__bf16)b[1]; r[6] = (__bf16)b[2]; r[7] = (__bf16)b[3];
  return r;
}

// ================= prep (blocks 0..384) + histogram (385..2884) =============
__global__ __launch_bounds__(256) void prep_hist(
    const float* __restrict__ W1a, const float* __restrict__ W2a,
    const float* __restrict__ W2b, const float* __restrict__ W1b,
    const float* __restrict__ b1b, const float* __restrict__ u,
    const int* __restrict__ EI,
    __bf16* __restrict__ WTya, __bf16* __restrict__ WTeb,
    __bf16* __restrict__ WT2c, __bf16* __restrict__ WT2bT,
    __bf16* __restrict__ WT2d, float* __restrict__ vtab,
    float* __restrict__ bc, int* __restrict__ cnt)
{
  int b = blockIdx.x, t = threadIdx.x;
  if (b >= 385) {                     // histogram: 2500 blocks cover NE
    int e = (b - 385) * 256 + t;
    atomicAdd(&cnt[EI[NE + e]], 1);
    return;
  }
  if (b < 64) {
    int idx = b * 256 + t; int n = idx & 127; int k = idx >> 7;
    WTya[n * 128 + k] = (__bf16)W1a[k * 128 + n];
  } else if (b < 96) {
    int idx = (b - 64) * 256 + t; int n = idx & 127; int k = idx >> 7;
    WTeb[n * 64 + k] = (__bf16)W1a[(128 + k) * 128 + n];
  } else if (b < 160) {
    int idx = (b - 96) * 256 + t; int n = idx & 127; int k = idx >> 7;
    WT2c[n * 128 + k] = (__bf16)W2a[k * 128 + n];
  } else if (b < 224) {
    int idx = (b - 160) * 256 + t; int n = idx & 127; int k = idx >> 7;
    WT2bT[n * 128 + k] = (__bf16)W2b[k * 128 + n];
  } else if (b < 256) {
    int idx = (b - 224) * 256 + t; int n = idx & 127; int gi = idx >> 7;
    float s0 = 0.f, s1 = 0.f;
    for (int k = 0; k < 64; k += 2) {
      s0 += u[gi * 64 + k] * W2a[(256 + k) * 128 + n];
      s1 += u[gi * 64 + k + 1] * W2a[(257 + k) * 128 + n];
    }
    vtab[gi * 128 + n] = s0 + s1;
  } else if (b == 256) {
    if (t < 128) {
      float s0 = 0.f, s1 = 0.f;
      for (int j = 0; j < 128; j += 2) {
        s0 += b1b[j] * W2a[(128 + j) * 128 + t];
        s1 += b1b[j + 1] * W2a[(129 + j) * 128 + t];
      }
      bc[t] = s0 + s1;
    }
  } else {
    int k = b - 257;                  // mean-feature index (pre-permute)
    if (t < 128) {
      float s0 = 0.f, s1 = 0.f;
      for (int j = 0; j < 128; j += 2) {
        s0 += W1b[k * 128 + j] * W2a[(128 + j) * 128 + t];
        s1 += W1b[k * 128 + j + 1] * W2a[(129 + j) * 128 + t];
      }
      int kp = ((k & 15) << 3) | (k >> 4);   // inverse of pi: pi(kp) == k
      WT2d[t * 128 + kp] = (__bf16)(s0 + s1);
    }
  }
}

// ================= scanA: block-local exclusive scan + block sums ===========
__global__ __launch_bounds__(256) void scanA(const int* __restrict__ cnt,
                                             int* __restrict__ offs,
                                             int* __restrict__ bsum) {
  __shared__ int sc[256];
  int i = blockIdx.x * 256 + threadIdx.x;
  int v = (i < NN) ? cnt[i] : 0;
  sc[threadIdx.x] = v;
  __syncthreads();
  for (int off = 1; off < 256; off <<= 1) {
    int t2 = (threadIdx.x >= off) ? sc[threadIdx.x - off] : 0;
    __syncthreads();
    sc[threadIdx.x] += t2;
    __syncthreads();
  }
  if (i < NN) offs[i] = sc[threadIdx.x] - v;      // exclusive within block
  if (threadIdx.x == 255) bsum[blockIdx.x] = sc[255];
}

// ================= fused: scanBC (blocks 0..156) | gemm_y (157..781) ========
__global__ __launch_bounds__(256) void scanBC_gemmy(
    int* __restrict__ offs, const int* __restrict__ bsum,
    const float* __restrict__ x, const __bf16* __restrict__ WTya,
    const float* __restrict__ b1a, __bf16* __restrict__ Yb)
{
  __shared__ int sc[256];
  if (blockIdx.x < 157) {
    int t = threadIdx.x;
    sc[t] = (t < 157) ? bsum[t] : 0;
    __syncthreads();
    for (int off = 1; off < 256; off <<= 1) {
      int t2 = (t >= off) ? sc[t - off] : 0;
      __syncthreads();
      sc[t] += t2;
      __syncthreads();
    }
    int base = (blockIdx.x > 0) ? sc[blockIdx.x - 1] : 0;
    int i = blockIdx.x * 256 + t;
    if (i < NN) offs[i] += base;
    return;
  }
  // ---- gemm_y: Yb (pi-packed) = x @ W1a_top + b1a ----
  int lane = threadIdx.x & 63;
  int wave = threadIdx.x >> 6;
  int rowbase = (blockIdx.x - 157) * 64 + wave * 16;
  int g = lane >> 4, c = lane & 15;

  f32x4v acc[8];
#pragma unroll
  for (int nt = 0; nt < 8; ++nt) acc[nt] = (f32x4v)(0.f);

  const float* arow = x + (size_t)(rowbase + c) * 128;
#pragma unroll
  for (int kk = 0; kk < 128; kk += 32) {
    bf16x8 af = cvt8(arow + kk + g * 8);
#pragma unroll
    for (int nt = 0; nt < 8; ++nt) {
      bf16x8 bf = *(const bf16x8*)(WTya + (nt * 16 + c) * 128 + kk + g * 8);
      acc[nt] = __builtin_amdgcn_mfma_f32_16x16x32_bf16(af, bf, acc[nt], 0, 0, 0);
    }
  }
  float bl[8];
#pragma unroll
  for (int nt = 0; nt < 8; ++nt) bl[nt] = b1a[nt * 16 + c];
#pragma unroll
  for (int q = 0; q < 4; ++q) {
    int r = rowbase + g * 4 + q;
    bf16x8 o;
#pragma unroll
    for (int nt = 0; nt < 8; ++nt) o[nt] = (__bf16)(acc[nt][q] + bl[nt]);
    *(bf16x8*)(Yb + (size_t)r * 128 + c * 8) = o;
  }
}

// ================= E: barrier-free per-wave pipelined edge GEMM =============
// Each wave: 4 tiles x 16 edges, private LDS double-buffer (no __syncthreads).
// Staging loads are lane-contiguous (lane l reads bytes l*64.. of the wave's
// 4KB tile). Next tile's loads issued before current tile's compute.
__global__ __launch_bounds__(256) void edge_E(
    const float* __restrict__ EA, const int* __restrict__ EI,
    int* __restrict__ offs,              // mutates to END offsets
    const __bf16* __restrict__ WTeb,
    const __bf16* __restrict__ Yb,       // pi-packed
    unsigned char* __restrict__ TMP8)    // 640000 x 128 fp8, pi-packed rows
{
  __shared__ __bf16 sm[4][2][16 * 136];
  int t = threadIdx.x;
  int lane = t & 63, w = t >> 6, g = lane >> 4, c = lane & 15;
  int lr = lane >> 2;                    // staging row 0..15
  int lc = (lane & 3) * 16;              // staging f32 col base
  size_t waveEdge0 = ((size_t)blockIdx.x * 4 + w) * (16 * TPW);
  const float* gbase = EA + waveEdge0 * 64;

  f32x4v bufA[4], bufB[4];
  // prologue: tile 0 (lane loads 64B contiguous)
#pragma unroll
  for (int j = 0; j < 4; ++j)
    bufA[j] = *(const f32x4v*)(gbase + (size_t)lr * 64 + lc + j * 4);

  for (int tile = 0; tile < TPW; ++tile) {
    __bf16* s = &sm[w][tile & 1][0];
    // stage: 16 f32 -> bf16, two 16B LDS writes (wave-private)
    {
      f32x4v a0 = bufA[0], a1 = bufA[1], a2 = bufA[2], a3 = bufA[3];
      bf16x8 v0, v1;
      v0[0] = (__bf16)a0[0]; v0[1] = (__bf16)a0[1]; v0[2] = (__bf16)a0[2]; v0[3] = (__bf16)a0[3];
      v0[4] = (__bf16)a1[0]; v0[5] = (__bf16)a1[1]; v0[6] = (__bf16)a1[2]; v0[7] = (__bf16)a1[3];
      v1[0] = (__bf16)a2[0]; v1[1] = (__bf16)a2[1]; v1[2] = (__bf16)a2[2]; v1[3] = (__bf16)a2[3];
      v1[4] = (__bf16)a3[0]; v1[5] = (__bf16)a3[1]; v1[6] = (__bf16)a3[2]; v1[7] = (__bf16)a3[3];
      *(bf16x8*)(s + lr * 136 + lc) = v0;
      *(bf16x8*)(s + lr * 136 + lc + 8) = v1;
    }
    // issue next tile's loads (in flight through this tile's compute)
    if (tile + 1 < TPW) {
      const float* tp = gbase + (size_t)(tile + 1) * 16 * 64;
#pragma unroll
      for (int j = 0; j < 4; ++j)
        bufB[j] = *(const f32x4v*)(tp + (size_t)lr * 64 + lc + j * 4);
    }
    // edge meta + sorted-slot alloc
    int e0 = (int)waveEdge0 + tile * 16;
    int myrow = 0, mypos = 0;
    if (lane < 16) {
      myrow = EI[e0 + lane];
      mypos = atomicAdd(&offs[EI[NE + e0 + lane]], 1);
    }

    // fragments from wave-private LDS (compiler inserts lgkmcnt waits)
    const __bf16* myr = s + c * 136;
    bf16x8 af0 = *(const bf16x8*)(myr + g * 8);
    bf16x8 af1 = *(const bf16x8*)(myr + 32 + g * 8);

    f32x4v acc[8];
#pragma unroll
    for (int nt = 0; nt < 8; ++nt) acc[nt] = (f32x4v)(0.f);
#pragma unroll
    for (int nt = 0; nt < 8; ++nt) {
      bf16x8 bf = *(const bf16x8*)(WTeb + (nt * 16 + c) * 64 + g * 8);
      acc[nt] = __builtin_amdgcn_mfma_f32_16x16x32_bf16(af0, bf, acc[nt], 0, 0, 0);
    }
#pragma unroll
    for (int nt = 0; nt < 8; ++nt) {
      bf16x8 bf = *(const bf16x8*)(WTeb + (nt * 16 + c) * 64 + 32 + g * 8);
      acc[nt] = __builtin_amdgcn_mfma_f32_16x16x32_bf16(af1, bf, acc[nt], 0, 0, 0);
    }

    // prefetch all 4 y-rows + slots, then compute + store
    int rows[4], poss[4];
    bf16x8 yvv[4];
#pragma unroll
    for (int q = 0; q < 4; ++q) {
      int src = g * 4 + q;
      rows[q] = __shfl(myrow, src, 64);
      poss[q] = __shfl(mypos, src, 64);
      yvv[q] = *(const bf16x8*)(Yb + (size_t)rows[q] * 128 + c * 8);
    }
#pragma unroll
    for (int q = 0; q < 4; ++q) {
      bf16x8 yv = yvv[q];
      float v0 = fmaxf(acc[0][q] + (float)yv[0], 0.f);
      float v1 = fmaxf(acc[1][q] + (float)yv[1], 0.f);
      float v2 = fmaxf(acc[2][q] + (float)yv[2], 0.f);
      float v3 = fmaxf(acc[3][q] + (float)yv[3], 0.f);
      float v4 = fmaxf(acc[4][q] + (float)yv[4], 0.f);
      float v5 = fmaxf(acc[5][q] + (float)yv[5], 0.f);
      float v6 = fmaxf(acc[6][q] + (float)yv[6], 0.f);
      float v7 = fmaxf(acc[7][q] + (float)yv[7], 0.f);
      unsigned lo = __builtin_amdgcn_cvt_pk_fp8_f32(v0, v1, 0, false);
      lo = __builtin_amdgcn_cvt_pk_fp8_f32(v2, v3, lo, true);
      unsigned hi = __builtin_amdgcn_cvt_pk_fp8_f32(v4, v5, 0, false);
      hi = __builtin_amdgcn_cvt_pk_fp8_f32(v6, v7, hi, true);
      u32x2v o; o[0] = lo; o[1] = hi;
      *(u32x2v*)(TMP8 + (size_t)poss[q] * 128 + c * 8) = o;
    }

    if (tile + 1 < TPW) {
#pragma unroll
      for (int k = 0; k < 4; ++k) bufA[k] = bufB[k];
    }
  }
}

// ================= fused mean + h1 + out GEMM ===============================
__global__ __launch_bounds__(256) void mlp_h1out(
    const unsigned int* __restrict__ TMP32,   // fp8 rows as 32 x u32
    const int* __restrict__ cnt, const int* __restrict__ offs,
    const float* __restrict__ x,
    const __bf16* __restrict__ WT2c, const __bf16* __restrict__ WT2d,
    const __bf16* __restrict__ WT2bT,
    const float* __restrict__ b2a, const float* __restrict__ bc,
    const float* __restrict__ vtab, const int* __restrict__ batch,
    const float* __restrict__ b2b, float* __restrict__ out)
{
  __shared__ __bf16 sb[64 * 136];       // mean (phase A/B), then h1 (B/C)
  int lane = threadIdx.x & 63;
  int w = threadIdx.x >> 6;
  int rowbase = blockIdx.x * 64 + w * 16;
  int g = lane >> 4, c = lane & 15;

  // ---- phase A: mean for this wave's 16 nodes ----
  {
    int p = lane >> 4, cu = lane & 15;  // row-slot 0..3, u32-pair col 0..15
    for (int nn = 0; nn < 16; ++nn) {
      int node = rowbase + nn;
      int m = cnt[node];
      int start = offs[node] - m;
      float s0 = 0.f, s1 = 0.f, s2 = 0.f, s3 = 0.f;
      float s4 = 0.f, s5 = 0.f, s6 = 0.f, s7 = 0.f;
      int iters = (m + 3) >> 2;
      for (int j = 0; j < iters; ++j) {
        int r = 4 * j + p;
        if (r < m) {
          u32x2v uu = *(const u32x2v*)(TMP32 + (size_t)(start + r) * 32 + cu * 2);
          f32x2v l0 = __builtin_amdgcn_cvt_pk_f32_fp8(uu[0], false);
          f32x2v h0 = __builtin_amdgcn_cvt_pk_f32_fp8(uu[0], true);
          f32x2v l1 = __builtin_amdgcn_cvt_pk_f32_fp8(uu[1], false);
          f32x2v h1 = __builtin_amdgcn_cvt_pk_f32_fp8(uu[1], true);
          s0 += l0[0]; s1 += l0[1]; s2 += h0[0]; s3 += h0[1];
          s4 += l1[0]; s5 += l1[1]; s6 += h1[0]; s7 += h1[1];
        }
      }
      s0 += __shfl_xor(s0, 16); s1 += __shfl_xor(s1, 16);
      s2 += __shfl_xor(s2, 16); s3 += __shfl_xor(s3, 16);
      s4 += __shfl_xor(s4, 16); s5 += __shfl_xor(s5, 16);
      s6 += __shfl_xor(s6, 16); s7 += __shfl_xor(s7, 16);
      s0 += __shfl_xor(s0, 32); s1 += __shfl_xor(s1, 32);
      s2 += __shfl_xor(s2, 32); s3 += __shfl_xor(s3, 32);
      s4 += __shfl_xor(s4, 32); s5 += __shfl_xor(s5, 32);
      s6 += __shfl_xor(s6, 32); s7 += __shfl_xor(s7, 32);
      if (p == 0) {
        float inv = 1.f / fmaxf((float)m, 1.f);
        bf16x8 o;
        o[0] = (__bf16)(s0 * inv); o[1] = (__bf16)(s1 * inv);
        o[2] = (__bf16)(s2 * inv); o[3] = (__bf16)(s3 * inv);
        o[4] = (__bf16)(s4 * inv); o[5] = (__bf16)(s5 * inv);
        o[6] = (__bf16)(s6 * inv); o[7] = (__bf16)(s7 * inv);
        *(bf16x8*)(sb + (w * 16 + nn) * 136 + cu * 8) = o;
      }
    }
  }

  // ---- phase B: acc = x@WT2c + mean@WT2d ----
  f32x4v acc[8];
#pragma unroll
  for (int nt = 0; nt < 8; ++nt) acc[nt] = (f32x4v)(0.f);

  const float* arow = x + (size_t)(rowbase + c) * 128;
#pragma unroll
  for (int kk = 0; kk < 128; kk += 32) {
    bf16x8 af = cvt8(arow + kk + g * 8);
#pragma unroll
    for (int nt = 0; nt < 8; ++nt) {
      bf16x8 bf = *(const bf16x8*)(WT2c + (nt * 16 + c) * 128 + kk + g * 8);
      acc[nt] = __builtin_amdgcn_mfma_f32_16x16x32_bf16(af, bf, acc[nt], 0, 0, 0);
    }
  }
  const __bf16* mrow = sb + (w * 16 + c) * 136;   // pi-packed mean (own wave)
#pragma unroll
  for (int kk = 0; kk < 128; kk += 32) {
    bf16x8 af = *(const bf16x8*)(mrow + kk + g * 8);
#pragma unroll
    for (int nt = 0; nt < 8; ++nt) {
      bf16x8 bf = *(const bf16x8*)(WT2d + (nt * 16 + c) * 128 + kk + g * 8);
      acc[nt] = __builtin_amdgcn_mfma_f32_16x16x32_bf16(af, bf, acc[nt], 0, 0, 0);
    }
  }

  // h1 = relu(acc + b2a + gate*bc + vtab[batch]) -> sb (own wave rows)
#pragma unroll
  for (int q = 0; q < 4; ++q) {
    int r = rowbase + g * 4 + q;
    float gmul = cnt[r] ? 1.f : 0.f;
    const float* vrow = vtab + (size_t)batch[r] * 128;
#pragma unroll
    for (int nt = 0; nt < 8; ++nt) {
      int n = nt * 16 + c;
      float v = acc[nt][q] + b2a[n] + gmul * bc[n] + vrow[n];
      sb[(w * 16 + g * 4 + q) * 136 + n] = (__bf16)fmaxf(v, 0.f);
    }
  }

  // ---- phase C: out = h1 @ WT2bT + b2b ----
  f32x4v acc2[8];
#pragma unroll
  for (int nt = 0; nt < 8; ++nt) acc2[nt] = (f32x4v)(0.f);

  const __bf16* hrow = sb + (w * 16 + c) * 136;
#pragma unroll
  for (int kk = 0; kk < 128; kk += 32) {
    bf16x8 af = *(const bf16x8*)(hrow + kk + g * 8);
#pragma unroll
    for (int nt = 0; nt < 8; ++nt) {
      bf16x8 bf = *(const bf16x8*)(WT2bT + (nt * 16 + c) * 128 + kk + g * 8);
      acc2[nt] = __builtin_amdgcn_mfma_f32_16x16x32_bf16(af, bf, acc2[nt], 0, 0, 0);
    }
  }
#pragma unroll
  for (int q = 0; q < 4; ++q) {
    int r = rowbase + g * 4 + q;
#pragma unroll
    for (int nt = 0; nt < 8; ++nt) {
      int n = nt * 16 + c;
      out[(size_t)r * 128 + n] = acc2[nt][q] + b2b[n];
    }
  }
}

// ================= host =====================================================
extern "C" void kernel_launch(void* const* d_in, const int* in_sizes, int n_in,
                              void* d_out, int out_size, void* d_ws, size_t ws_size,
                              hipStream_t stream) {
  const float* x    = (const float*)d_in[0];
  const int*   ei   = (const int*)d_in[1];
  const float* ea   = (const float*)d_in[2];
  const float* u    = (const float*)d_in[3];
  const int*   batch= (const int*)d_in[4];
  const float* W1a  = (const float*)d_in[5];
  const float* b1a  = (const float*)d_in[6];
  const float* W1b  = (const float*)d_in[7];
  const float* b1b  = (const float*)d_in[8];
  const float* W2a  = (const float*)d_in[9];
  const float* b2a  = (const float*)d_in[10];
  const float* W2b  = (const float*)d_in[11];
  const float* b2b  = (const float*)d_in[12];

  char* ws = (char*)d_ws;
  __bf16* WTya  = (__bf16*)(ws);              // 32768
  __bf16* WTeb  = (__bf16*)(ws + 32768);      // 16384
  __bf16* WT2c  = (__bf16*)(ws + 49152);      // 32768
  __bf16* WT2bT = (__bf16*)(ws + 81920);      // 32768
  __bf16* WT2d  = (__bf16*)(ws + 114688);     // 32768
  float*  vtab  = (float*)(ws + 147456);      // 32768
  float*  bc    = (float*)(ws + 180224);      // 512
  int*    cnt   = (int*)(ws + 180736);        // 160,000
  int*    offs  = (int*)(ws + 340736);        // 160,000
  int*    bsum  = (int*)(ws + 500736);        // 1,024
  __bf16* Yb    = (__bf16*)(ws + 3061760);    // 10,240,000
  unsigned char* TMP8 = (unsigned char*)(ws + 13301760); // 81,920,000 -> 95.2 MB

  hipMemsetAsync(cnt, 0, 160000, stream);
  prep_hist<<<2885, 256, 0, stream>>>(W1a, W2a, W2b, W1b, b1b, u, ei,
                                      WTya, WTeb, WT2c, WT2bT, WT2d,
                                      vtab, bc, cnt);
  scanA<<<157, 256, 0, stream>>>(cnt, offs, bsum);
  scanBC_gemmy<<<782, 256, 0, stream>>>(offs, bsum, x, WTya, b1a, Yb);
  edge_E<<<NE / (64 * TPW), 256, 0, stream>>>(ea, ei, offs, WTeb, Yb, TMP8);
  mlp_h1out<<<625, 256, 0, stream>>>((const unsigned int*)TMP8, cnt, offs, x,
                                     WT2c, WT2d, WT2bT, b2a, bc, vtab, batch,
                                     b2b, (float*)d_out);
}

// Round 15
// 219.148 us; speedup vs baseline: 1.1199x; 1.1199x over previous
//
#include <hip/hip_runtime.h>
#include <hip/hip_bf16.h>

// NodeModel fused GNN block, round 15 = round 13 base + corrected barrier-free
// per-wave pipelined edge_E:
//   - staging loads PERFECTLY dense (lane l -> tile + l*16, contiguous 1KB/instr)
//   - wave-private 16-edge LDS tiles (stride 72, 2-way = free), NO __syncthreads
//   - LDS 18.4KB/block (was 34.8) -> 2x resident-block headroom; TPW=4, grid 2500
//   memset cnt; prep_hist; scanA; [scanBC|gemm_y]; edge_E; mlp_h1out

typedef __bf16 bf16x8 __attribute__((ext_vector_type(8)));
typedef __bf16 bf16x4 __attribute__((ext_vector_type(4)));
typedef float f32x4v __attribute__((ext_vector_type(4)));
typedef float f32x2v __attribute__((ext_vector_type(2)));
typedef unsigned int u32x2v __attribute__((ext_vector_type(2)));

#define NN 40000
#define NE 640000
#define TPW 4   // tiles (of 16 edges) per wave

__device__ inline bf16x8 cvt8(const float* __restrict__ p) {
  f32x4v a = *(const f32x4v*)p;
  f32x4v b = *(const f32x4v*)(p + 4);
  bf16x8 r;
  r[0] = (__bf16)a[0]; r[1] = (__bf16)a[1]; r[2] = (__bf16)a[2]; r[3] = (__bf16)a[3];
  r[4] = (__bf16)b[0]; r[5] = (__bf16)b[1]; r[6] = (__bf16)b[2]; r[7] = (__bf16)b[3];
  return r;
}

// ================= prep (blocks 0..384) + histogram (385..2884) =============
__global__ __launch_bounds__(256) void prep_hist(
    const float* __restrict__ W1a, const float* __restrict__ W2a,
    const float* __restrict__ W2b, const float* __restrict__ W1b,
    const float* __restrict__ b1b, const float* __restrict__ u,
    const int* __restrict__ EI,
    __bf16* __restrict__ WTya, __bf16* __restrict__ WTeb,
    __bf16* __restrict__ WT2c, __bf16* __restrict__ WT2bT,
    __bf16* __restrict__ WT2d, float* __restrict__ vtab,
    float* __restrict__ bc, int* __restrict__ cnt)
{
  int b = blockIdx.x, t = threadIdx.x;
  if (b >= 385) {                     // histogram: 2500 blocks cover NE
    int e = (b - 385) * 256 + t;
    atomicAdd(&cnt[EI[NE + e]], 1);
    return;
  }
  if (b < 64) {
    int idx = b * 256 + t; int n = idx & 127; int k = idx >> 7;
    WTya[n * 128 + k] = (__bf16)W1a[k * 128 + n];
  } else if (b < 96) {
    int idx = (b - 64) * 256 + t; int n = idx & 127; int k = idx >> 7;
    WTeb[n * 64 + k] = (__bf16)W1a[(128 + k) * 128 + n];
  } else if (b < 160) {
    int idx = (b - 96) * 256 + t; int n = idx & 127; int k = idx >> 7;
    WT2c[n * 128 + k] = (__bf16)W2a[k * 128 + n];
  } else if (b < 224) {
    int idx = (b - 160) * 256 + t; int n = idx & 127; int k = idx >> 7;
    WT2bT[n * 128 + k] = (__bf16)W2b[k * 128 + n];
  } else if (b < 256) {
    int idx = (b - 224) * 256 + t; int n = idx & 127; int gi = idx >> 7;
    float s0 = 0.f, s1 = 0.f;
    for (int k = 0; k < 64; k += 2) {
      s0 += u[gi * 64 + k] * W2a[(256 + k) * 128 + n];
      s1 += u[gi * 64 + k + 1] * W2a[(257 + k) * 128 + n];
    }
    vtab[gi * 128 + n] = s0 + s1;
  } else if (b == 256) {
    if (t < 128) {
      float s0 = 0.f, s1 = 0.f;
      for (int j = 0; j < 128; j += 2) {
        s0 += b1b[j] * W2a[(128 + j) * 128 + t];
        s1 += b1b[j + 1] * W2a[(129 + j) * 128 + t];
      }
      bc[t] = s0 + s1;
    }
  } else {
    int k = b - 257;                  // mean-feature index (pre-permute)
    if (t < 128) {
      float s0 = 0.f, s1 = 0.f;
      for (int j = 0; j < 128; j += 2) {
        s0 += W1b[k * 128 + j] * W2a[(128 + j) * 128 + t];
        s1 += W1b[k * 128 + j + 1] * W2a[(129 + j) * 128 + t];
      }
      int kp = ((k & 15) << 3) | (k >> 4);   // inverse of pi: pi(kp) == k
      WT2d[t * 128 + kp] = (__bf16)(s0 + s1);
    }
  }
}

// ================= scanA: block-local exclusive scan + block sums ===========
__global__ __launch_bounds__(256) void scanA(const int* __restrict__ cnt,
                                             int* __restrict__ offs,
                                             int* __restrict__ bsum) {
  __shared__ int sc[256];
  int i = blockIdx.x * 256 + threadIdx.x;
  int v = (i < NN) ? cnt[i] : 0;
  sc[threadIdx.x] = v;
  __syncthreads();
  for (int off = 1; off < 256; off <<= 1) {
    int t2 = (threadIdx.x >= off) ? sc[threadIdx.x - off] : 0;
    __syncthreads();
    sc[threadIdx.x] += t2;
    __syncthreads();
  }
  if (i < NN) offs[i] = sc[threadIdx.x] - v;      // exclusive within block
  if (threadIdx.x == 255) bsum[blockIdx.x] = sc[255];
}

// ================= fused: scanBC (blocks 0..156) | gemm_y (157..781) ========
__global__ __launch_bounds__(256) void scanBC_gemmy(
    int* __restrict__ offs, const int* __restrict__ bsum,
    const float* __restrict__ x, const __bf16* __restrict__ WTya,
    const float* __restrict__ b1a, __bf16* __restrict__ Yb)
{
  __shared__ int sc[256];
  if (blockIdx.x < 157) {
    int t = threadIdx.x;
    sc[t] = (t < 157) ? bsum[t] : 0;
    __syncthreads();
    for (int off = 1; off < 256; off <<= 1) {
      int t2 = (t >= off) ? sc[t - off] : 0;
      __syncthreads();
      sc[t] += t2;
      __syncthreads();
    }
    int base = (blockIdx.x > 0) ? sc[blockIdx.x - 1] : 0;
    int i = blockIdx.x * 256 + t;
    if (i < NN) offs[i] += base;
    return;
  }
  // ---- gemm_y: Yb (pi-packed) = x @ W1a_top + b1a ----
  int lane = threadIdx.x & 63;
  int wave = threadIdx.x >> 6;
  int rowbase = (blockIdx.x - 157) * 64 + wave * 16;
  int g = lane >> 4, c = lane & 15;

  f32x4v acc[8];
#pragma unroll
  for (int nt = 0; nt < 8; ++nt) acc[nt] = (f32x4v)(0.f);

  const float* arow = x + (size_t)(rowbase + c) * 128;
#pragma unroll
  for (int kk = 0; kk < 128; kk += 32) {
    bf16x8 af = cvt8(arow + kk + g * 8);
#pragma unroll
    for (int nt = 0; nt < 8; ++nt) {
      bf16x8 bf = *(const bf16x8*)(WTya + (nt * 16 + c) * 128 + kk + g * 8);
      acc[nt] = __builtin_amdgcn_mfma_f32_16x16x32_bf16(af, bf, acc[nt], 0, 0, 0);
    }
  }
  float bl[8];
#pragma unroll
  for (int nt = 0; nt < 8; ++nt) bl[nt] = b1a[nt * 16 + c];
#pragma unroll
  for (int q = 0; q < 4; ++q) {
    int r = rowbase + g * 4 + q;
    bf16x8 o;
#pragma unroll
    for (int nt = 0; nt < 8; ++nt) o[nt] = (__bf16)(acc[nt][q] + bl[nt]);
    *(bf16x8*)(Yb + (size_t)r * 128 + c * 8) = o;
  }
}

// ================= E: barrier-free per-wave pipelined edge GEMM =============
// Wave owns 4 tiles x 16 edges + private LDS double-buffer (stride 72 bf16).
// Staging: lane l loads 16B at tile+l*16 (4 instrs, each a dense 1KB run);
// chunk j of lane l -> row j*4+(l>>4), f32 cols (l&15)*4 -> one 8B LDS write.
// No __syncthreads anywhere; intra-wave lgkmcnt only.
__global__ __launch_bounds__(256) void edge_E(
    const float* __restrict__ EA, const int* __restrict__ EI,
    int* __restrict__ offs,              // mutates to END offsets
    const __bf16* __restrict__ WTeb,
    const __bf16* __restrict__ Yb,       // pi-packed
    unsigned char* __restrict__ TMP8)    // 640000 x 128 fp8, pi-packed rows
{
  __shared__ __bf16 sm[4][2][16 * 72];   // 18,432 B / block
  int t = threadIdx.x;
  int lane = t & 63, w = t >> 6, g = lane >> 4, c = lane & 15;
  int srow = lane >> 4;                  // + j*4 = staging row
  int scol = (lane & 15) * 4;            // staging f32 col
  size_t waveEdge0 = ((size_t)blockIdx.x * 4 + w) * (16 * TPW);
  const float* gbase = EA + waveEdge0 * 64;

  f32x4v bufA[4], bufB[4];
  // prologue: tile 0, perfectly dense (instr j covers contiguous 1KB)
#pragma unroll
  for (int j = 0; j < 4; ++j)
    bufA[j] = *(const f32x4v*)(gbase + j * 256 + lane * 4);

  for (int tile = 0; tile < TPW; ++tile) {
    __bf16* s = &sm[w][tile & 1][0];
    // stage: 4 x (4 f32 -> bf16x4 -> 8B LDS write), conflict-free
#pragma unroll
    for (int j = 0; j < 4; ++j) {
      f32x4v a = bufA[j];
      bf16x4 v;
      v[0] = (__bf16)a[0]; v[1] = (__bf16)a[1];
      v[2] = (__bf16)a[2]; v[3] = (__bf16)a[3];
      *(bf16x4*)(s + (j * 4 + srow) * 72 + scol) = v;
    }
    // issue next tile's loads (in flight through this tile's compute)
    if (tile + 1 < TPW) {
      const float* tp = gbase + (size_t)(tile + 1) * 1024;
#pragma unroll
      for (int j = 0; j < 4; ++j)
        bufB[j] = *(const f32x4v*)(tp + j * 256 + lane * 4);
    }
    // edge meta + sorted-slot alloc
    int e0 = (int)waveEdge0 + tile * 16;
    int myrow = 0, mypos = 0;
    if (lane < 16) {
      myrow = EI[e0 + lane];
      mypos = atomicAdd(&offs[EI[NE + e0 + lane]], 1);
    }

    // fragments from wave-private LDS (2-way bank alias = free)
    const __bf16* myr = s + c * 72;
    bf16x8 af0 = *(const bf16x8*)(myr + g * 8);
    bf16x8 af1 = *(const bf16x8*)(myr + 32 + g * 8);

    f32x4v acc[8];
#pragma unroll
    for (int nt = 0; nt < 8; ++nt) acc[nt] = (f32x4v)(0.f);
#pragma unroll
    for (int nt = 0; nt < 8; ++nt) {
      bf16x8 bf = *(const bf16x8*)(WTeb + (nt * 16 + c) * 64 + g * 8);
      acc[nt] = __builtin_amdgcn_mfma_f32_16x16x32_bf16(af0, bf, acc[nt], 0, 0, 0);
    }
#pragma unroll
    for (int nt = 0; nt < 8; ++nt) {
      bf16x8 bf = *(const bf16x8*)(WTeb + (nt * 16 + c) * 64 + 32 + g * 8);
      acc[nt] = __builtin_amdgcn_mfma_f32_16x16x32_bf16(af1, bf, acc[nt], 0, 0, 0);
    }

    // prefetch all 4 y-rows + slots, then compute + store
    int rows[4], poss[4];
    bf16x8 yvv[4];
#pragma unroll
    for (int q = 0; q < 4; ++q) {
      int src = g * 4 + q;
      rows[q] = __shfl(myrow, src, 64);
      poss[q] = __shfl(mypos, src, 64);
      yvv[q] = *(const bf16x8*)(Yb + (size_t)rows[q] * 128 + c * 8);
    }
#pragma unroll
    for (int q = 0; q < 4; ++q) {
      bf16x8 yv = yvv[q];
      float v0 = fmaxf(acc[0][q] + (float)yv[0], 0.f);
      float v1 = fmaxf(acc[1][q] + (float)yv[1], 0.f);
      float v2 = fmaxf(acc[2][q] + (float)yv[2], 0.f);
      float v3 = fmaxf(acc[3][q] + (float)yv[3], 0.f);
      float v4 = fmaxf(acc[4][q] + (float)yv[4], 0.f);
      float v5 = fmaxf(acc[5][q] + (float)yv[5], 0.f);
      float v6 = fmaxf(acc[6][q] + (float)yv[6], 0.f);
      float v7 = fmaxf(acc[7][q] + (float)yv[7], 0.f);
      unsigned lo = __builtin_amdgcn_cvt_pk_fp8_f32(v0, v1, 0, false);
      lo = __builtin_amdgcn_cvt_pk_fp8_f32(v2, v3, lo, true);
      unsigned hi = __builtin_amdgcn_cvt_pk_fp8_f32(v4, v5, 0, false);
      hi = __builtin_amdgcn_cvt_pk_fp8_f32(v6, v7, hi, true);
      u32x2v o; o[0] = lo; o[1] = hi;
      *(u32x2v*)(TMP8 + (size_t)poss[q] * 128 + c * 8) = o;
    }

    if (tile + 1 < TPW) {
#pragma unroll
      for (int k = 0; k < 4; ++k) bufA[k] = bufB[k];
    }
  }
}

// ================= fused mean + h1 + out GEMM ===============================
__global__ __launch_bounds__(256) void mlp_h1out(
    const unsigned int* __restrict__ TMP32,   // fp8 rows as 32 x u32
    const int* __restrict__ cnt, const int* __restrict__ offs,
    const float* __restrict__ x,
    const __bf16* __restrict__ WT2c, const __bf16* __restrict__ WT2d,
    const __bf16* __restrict__ WT2bT,
    const float* __restrict__ b2a, const float* __restrict__ bc,
    const float* __restrict__ vtab, const int* __restrict__ batch,
    const float* __restrict__ b2b, float* __restrict__ out)
{
  __shared__ __bf16 sb[64 * 136];       // mean (phase A/B), then h1 (B/C)
  int lane = threadIdx.x & 63;
  int w = threadIdx.x >> 6;
  int rowbase = blockIdx.x * 64 + w * 16;
  int g = lane >> 4, c = lane & 15;

  // ---- phase A: mean for this wave's 16 nodes ----
  {
    int p = lane >> 4, cu = lane & 15;  // row-slot 0..3, u32-pair col 0..15
    for (int nn = 0; nn < 16; ++nn) {
      int node = rowbase + nn;
      int m = cnt[node];
      int start = offs[node] - m;
      float s0 = 0.f, s1 = 0.f, s2 = 0.f, s3 = 0.f;
      float s4 = 0.f, s5 = 0.f, s6 = 0.f, s7 = 0.f;
      int iters = (m + 3) >> 2;
      for (int j = 0; j < iters; ++j) {
        int r = 4 * j + p;
        if (r < m) {
          u32x2v uu = *(const u32x2v*)(TMP32 + (size_t)(start + r) * 32 + cu * 2);
          f32x2v l0 = __builtin_amdgcn_cvt_pk_f32_fp8(uu[0], false);
          f32x2v h0 = __builtin_amdgcn_cvt_pk_f32_fp8(uu[0], true);
          f32x2v l1 = __builtin_amdgcn_cvt_pk_f32_fp8(uu[1], false);
          f32x2v h1 = __builtin_amdgcn_cvt_pk_f32_fp8(uu[1], true);
          s0 += l0[0]; s1 += l0[1]; s2 += h0[0]; s3 += h0[1];
          s4 += l1[0]; s5 += l1[1]; s6 += h1[0]; s7 += h1[1];
        }
      }
      s0 += __shfl_xor(s0, 16); s1 += __shfl_xor(s1, 16);
      s2 += __shfl_xor(s2, 16); s3 += __shfl_xor(s3, 16);
      s4 += __shfl_xor(s4, 16); s5 += __shfl_xor(s5, 16);
      s6 += __shfl_xor(s6, 16); s7 += __shfl_xor(s7, 16);
      s0 += __shfl_xor(s0, 32); s1 += __shfl_xor(s1, 32);
      s2 += __shfl_xor(s2, 32); s3 += __shfl_xor(s3, 32);
      s4 += __shfl_xor(s4, 32); s5 += __shfl_xor(s5, 32);
      s6 += __shfl_xor(s6, 32); s7 += __shfl_xor(s7, 32);
      if (p == 0) {
        float inv = 1.f / fmaxf((float)m, 1.f);
        bf16x8 o;
        o[0] = (__bf16)(s0 * inv); o[1] = (__bf16)(s1 * inv);
        o[2] = (__bf16)(s2 * inv); o[3] = (__bf16)(s3 * inv);
        o[4] = (__bf16)(s4 * inv); o[5] = (__bf16)(s5 * inv);
        o[6] = (__bf16)(s6 * inv); o[7] = (__bf16)(s7 * inv);
        *(bf16x8*)(sb + (w * 16 + nn) * 136 + cu * 8) = o;
      }
    }
  }

  // ---- phase B: acc = x@WT2c + mean@WT2d ----
  f32x4v acc[8];
#pragma unroll
  for (int nt = 0; nt < 8; ++nt) acc[nt] = (f32x4v)(0.f);

  const float* arow = x + (size_t)(rowbase + c) * 128;
#pragma unroll
  for (int kk = 0; kk < 128; kk += 32) {
    bf16x8 af = cvt8(arow + kk + g * 8);
#pragma unroll
    for (int nt = 0; nt < 8; ++nt) {
      bf16x8 bf = *(const bf16x8*)(WT2c + (nt * 16 + c) * 128 + kk + g * 8);
      acc[nt] = __builtin_amdgcn_mfma_f32_16x16x32_bf16(af, bf, acc[nt], 0, 0, 0);
    }
  }
  const __bf16* mrow = sb + (w * 16 + c) * 136;   // pi-packed mean (own wave)
#pragma unroll
  for (int kk = 0; kk < 128; kk += 32) {
    bf16x8 af = *(const bf16x8*)(mrow + kk + g * 8);
#pragma unroll
    for (int nt = 0; nt < 8; ++nt) {
      bf16x8 bf = *(const bf16x8*)(WT2d + (nt * 16 + c) * 128 + kk + g * 8);
      acc[nt] = __builtin_amdgcn_mfma_f32_16x16x32_bf16(af, bf, acc[nt], 0, 0, 0);
    }
  }

  // h1 = relu(acc + b2a + gate*bc + vtab[batch]) -> sb (own wave rows)
#pragma unroll
  for (int q = 0; q < 4; ++q) {
    int r = rowbase + g * 4 + q;
    float gmul = cnt[r] ? 1.f : 0.f;
    const float* vrow = vtab + (size_t)batch[r] * 128;
#pragma unroll
    for (int nt = 0; nt < 8; ++nt) {
      int n = nt * 16 + c;
      float v = acc[nt][q] + b2a[n] + gmul * bc[n] + vrow[n];
      sb[(w * 16 + g * 4 + q) * 136 + n] = (__bf16)fmaxf(v, 0.f);
    }
  }

  // ---- phase C: out = h1 @ WT2bT + b2b ----
  f32x4v acc2[8];
#pragma unroll
  for (int nt = 0; nt < 8; ++nt) acc2[nt] = (f32x4v)(0.f);

  const __bf16* hrow = sb + (w * 16 + c) * 136;
#pragma unroll
  for (int kk = 0; kk < 128; kk += 32) {
    bf16x8 af = *(const bf16x8*)(hrow + kk + g * 8);
#pragma unroll
    for (int nt = 0; nt < 8; ++nt) {
      bf16x8 bf = *(const bf16x8*)(WT2bT + (nt * 16 + c) * 128 + kk + g * 8);
      acc2[nt] = __builtin_amdgcn_mfma_f32_16x16x32_bf16(af, bf, acc2[nt], 0, 0, 0);
    }
  }
#pragma unroll
  for (int q = 0; q < 4; ++q) {
    int r = rowbase + g * 4 + q;
#pragma unroll
    for (int nt = 0; nt < 8; ++nt) {
      int n = nt * 16 + c;
      out[(size_t)r * 128 + n] = acc2[nt][q] + b2b[n];
    }
  }
}

// ================= host =====================================================
extern "C" void kernel_launch(void* const* d_in, const int* in_sizes, int n_in,
                              void* d_out, int out_size, void* d_ws, size_t ws_size,
                              hipStream_t stream) {
  const float* x    = (const float*)d_in[0];
  const int*   ei   = (const int*)d_in[1];
  const float* ea   = (const float*)d_in[2];
  const float* u    = (const float*)d_in[3];
  const int*   batch= (const int*)d_in[4];
  const float* W1a  = (const float*)d_in[5];
  const float* b1a  = (const float*)d_in[6];
  const float* W1b  = (const float*)d_in[7];
  const float* b1b  = (const float*)d_in[8];
  const float* W2a  = (const float*)d_in[9];
  const float* b2a  = (const float*)d_in[10];
  const float* W2b  = (const float*)d_in[11];
  const float* b2b  = (const float*)d_in[12];

  char* ws = (char*)d_ws;
  __bf16* WTya  = (__bf16*)(ws);              // 32768
  __bf16* WTeb  = (__bf16*)(ws + 32768);      // 16384
  __bf16* WT2c  = (__bf16*)(ws + 49152);      // 32768
  __bf16* WT2bT = (__bf16*)(ws + 81920);      // 32768
  __bf16* WT2d  = (__bf16*)(ws + 114688);     // 32768
  float*  vtab  = (float*)(ws + 147456);      // 32768
  float*  bc    = (float*)(ws + 180224);      // 512
  int*    cnt   = (int*)(ws + 180736);        // 160,000
  int*    offs  = (int*)(ws + 340736);        // 160,000
  int*    bsum  = (int*)(ws + 500736);        // 1,024
  __bf16* Yb    = (__bf16*)(ws + 3061760);    // 10,240,000
  unsigned char* TMP8 = (unsigned char*)(ws + 13301760); // 81,920,000 -> 95.2 MB

  hipMemsetAsync(cnt, 0, 160000, stream);
  prep_hist<<<2885, 256, 0, stream>>>(W1a, W2a, W2b, W1b, b1b, u, ei,
                                      WTya, WTeb, WT2c, WT2bT, WT2d,
                                      vtab, bc, cnt);
  scanA<<<157, 256, 0, stream>>>(cnt, offs, bsum);
  scanBC_gemmy<<<782, 256, 0, stream>>>(offs, bsum, x, WTya, b1a, Yb);
  edge_E<<<NE / (64 * TPW), 256, 0, stream>>>(ea, ei, offs, WTeb, Yb, TMP8);
  mlp_h1out<<<625, 256, 0, stream>>>((const unsigned int*)TMP8, cnt, offs, x,
                                     WT2c, WT2d, WT2bT, b2a, bc, vtab, batch,
                                     b2b, (float*)d_out);
}